// Round 1
// baseline (427.128 us; speedup 1.0000x reference)
//
#include <hip/hip_runtime.h>
#include <hip/hip_bf16.h>
#include <stdint.h>

typedef __attribute__((ext_vector_type(8))) short bf16x8;
typedef __attribute__((ext_vector_type(4))) float f32x4;
typedef unsigned short u16;
typedef unsigned int u32;

__device__ __forceinline__ u16 f2bf_rne(float v) {
    u32 u = __float_as_uint(v);
    u32 r = (u + 0x7fffu + ((u >> 16) & 1u)) >> 16;
    return (u16)r;
}

// ---------------- pack kernels ----------------

// x (2048,39,16) f32  ->  xbd [32768][40] bf16, m = b*16+d, col 39 zero-pad
__global__ void pack_x_kernel(const float* __restrict__ x, u16* __restrict__ xbd) {
    int idx = blockIdx.x * 256 + threadIdx.x;
    if (idx >= 32768 * 40) return;
    int m = idx / 40, f = idx - m * 40;
    int b = m >> 4, d = m & 15;
    float v = (f < 39) ? x[(b * 39 + f) * 16 + d] : 0.0f;
    xbd[idx] = f2bf_rne(v);
}

// W0 (200,39,39) f32 -> Wp [208][1600] bf16, k = f*40+g, zero-padded
__global__ void pack_w0_kernel(const float* __restrict__ W, u16* __restrict__ Wp) {
    int idx = blockIdx.x * 256 + threadIdx.x;
    if (idx >= 208 * 1600) return;
    int o = idx / 1600, k = idx - o * 1600;
    int f = k / 40, g = k - f * 40;
    float v = (o < 200 && f < 39 && g < 39) ? W[(o * 39 + f) * 39 + g] : 0.0f;
    Wp[idx] = f2bf_rne(v);
}

// W1/W2 (200,39,200) f32 -> Wp [208][7808] bf16, k = f*200+g (linear copy), zero-padded
__global__ void pack_w12_kernel(const float* __restrict__ W, u16* __restrict__ Wp) {
    int idx = blockIdx.x * 256 + threadIdx.x;
    if (idx >= 208 * 7808) return;
    int o = idx / 7808, k = idx - o * 7808;
    float v = (o < 200 && k < 7800) ? W[o * 7800 + k] : 0.0f;
    Wp[idx] = f2bf_rne(v);
}

// ---------------- main GEMM kernel ----------------
// C[m,o] = sum_k A[m,k]*Wp[o,k],  A[m, f*GP+g] = xbd[m,f]*h[m,g]
// block: 256 thr (4 waves), M_tile=128, N half-tile (112 or 96 cols)
template <int LAYER>
__global__ __launch_bounds__(256, 2) void cin_gemm_kernel(
    const u16* __restrict__ Xbd,    // [32768][40] bf16
    const u16* __restrict__ Hin,    // [32768][208] bf16 (LAYER>0)
    const u16* __restrict__ Wp,     // [208][KP] bf16
    const float* __restrict__ bias, // [200] f32
    u16* __restrict__ Hout,         // [32768][208] bf16 (LAYER<2)
    float* __restrict__ out)        // [2048][600] f32
{
    constexpr int GP   = (LAYER == 0) ? 40 : 200;
    constexpr int KP   = (LAYER == 0) ? 1600 : 7808;
    constexpr int NC   = KP / 32;
    constexpr int HSTR = 216;   // LDS row stride for H (12-bank row step -> <=2-way)

    __shared__ u16 Xlds[128 * 40];
    __shared__ u16 Wlds[112 * 40];   // k-chunk: [Ntile rows][32k + 8 pad]
    __shared__ u16 Hlds[(LAYER == 0) ? 8 : 128 * HSTR];

    const int bid = blockIdx.x;
    const int mblk = bid >> 1, nblk = bid & 1;
    const int m0 = mblk * 128;
    const int ncol0 = nblk ? 112 : 0;
    const int NT = nblk ? 6 : 7;          // 16-wide N tiles in this block
    const int TROWS4 = NT * 16 * 4;       // 16B units per W chunk
    const int tid = threadIdx.x;
    const int lane = tid & 63, wid = tid >> 6;
    const int wM = wid >> 1, wN = wid & 1;
    const int tLo = wN ? ((NT + 1) >> 1) : 0;
    const int nTw = (wN ? NT : ((NT + 1) >> 1)) - tLo;   // 4 or 3
    const int rowl = lane & 15;
    const int grp  = lane >> 4;

    // ---- stage X tile (once) ----
    for (int u = tid; u < 128 * 5; u += 256) {
        int r = u / 5, q = u - r * 5;
        *reinterpret_cast<int4*>(&Xlds[r * 40 + q * 8]) =
            *reinterpret_cast<const int4*>(&Xbd[(size_t)(m0 + r) * 40 + q * 8]);
    }
    // ---- stage H tile (once) ----
    if constexpr (LAYER > 0) {
        for (int u = tid; u < 128 * 26; u += 256) {
            int r = u / 26, q = u - r * 26;
            *reinterpret_cast<int4*>(&Hlds[r * HSTR + q * 8]) =
                *reinterpret_cast<const int4*>(&Hin[(size_t)(m0 + r) * 208 + q * 8]);
        }
    }

    // ---- W chunk 0: global -> regs -> LDS ----
    const int wr0 = tid >> 2, wq0 = tid & 3;
    const int u1  = tid + 256;
    const int wr1 = u1 >> 2, wq1 = u1 & 3;
    int4 wreg0, wreg1;
    wreg0 = *reinterpret_cast<const int4*>(&Wp[(size_t)(ncol0 + wr0) * KP + wq0 * 8]);
    if (u1 < TROWS4)
        wreg1 = *reinterpret_cast<const int4*>(&Wp[(size_t)(ncol0 + wr1) * KP + wq1 * 8]);
    *reinterpret_cast<int4*>(&Wlds[wr0 * 40 + wq0 * 8]) = wreg0;
    if (u1 < TROWS4)
        *reinterpret_cast<int4*>(&Wlds[wr1 * 40 + wq1 * 8]) = wreg1;

    // per-subtile LDS row bases
    int xbase[4], hbase[4];
    #pragma unroll
    for (int s = 0; s < 4; ++s) {
        int r = wM * 64 + s * 16 + rowl;
        xbase[s] = r * 40;
        hbase[s] = (LAYER == 0) ? r * 40 : r * HSTR;
    }

    f32x4 acc[4][4];
    #pragma unroll
    for (int s = 0; s < 4; ++s) {
        #pragma unroll
        for (int t = 0; t < 4; ++t) {
            f32x4 z = {0.f, 0.f, 0.f, 0.f};
            acc[s][t] = z;
        }
    }

    for (int kc = 0; kc < NC; ++kc) {
        __syncthreads();   // Wlds[kc] + X/H visible
        // prefetch next W chunk to regs (lands during compute)
        if (kc + 1 < NC) {
            int kb = (kc + 1) * 32;
            wreg0 = *reinterpret_cast<const int4*>(&Wp[(size_t)(ncol0 + wr0) * KP + kb + wq0 * 8]);
            if (u1 < TROWS4)
                wreg1 = *reinterpret_cast<const int4*>(&Wp[(size_t)(ncol0 + wr1) * KP + kb + wq1 * 8]);
        }
        // ---- build A fragments: A[m, k] = x[m,f] * h[m,g],  8 consecutive g per lane ----
        int k0 = kc * 32 + grp * 8;
        int f  = k0 / GP;
        int g0 = k0 - f * GP;
        bf16x8 afrag[4];
        #pragma unroll
        for (int s = 0; s < 4; ++s) {
            u16 xs = Xlds[xbase[s] + f];
            bf16x8 hv;
            if constexpr (LAYER == 0)
                hv = *reinterpret_cast<const bf16x8*>(&Xlds[hbase[s] + g0]);
            else
                hv = *reinterpret_cast<const bf16x8*>(&Hlds[hbase[s] + g0]);
            float xf = __uint_as_float(((u32)xs) << 16);
            union { bf16x8 v; u32 w[4]; } hu, au;
            hu.v = hv;
            #pragma unroll
            for (int j = 0; j < 4; ++j) {
                float lo = __uint_as_float(hu.w[j] << 16);
                float hi = __uint_as_float(hu.w[j] & 0xffff0000u);
                float pl = xf * lo;
                float ph = xf * hi;
                u32 pk;
                asm("v_cvt_pk_bf16_f32 %0, %1, %2" : "=v"(pk) : "v"(pl), "v"(ph));
                au.w[j] = pk;
            }
            afrag[s] = au.v;
        }
        // ---- B fragments + MFMA ----
        #pragma unroll
        for (int tt = 0; tt < 4; ++tt) {
            if (tt < nTw) {
                int t = tLo + tt;
                bf16x8 bfrag = *reinterpret_cast<const bf16x8*>(&Wlds[(t * 16 + rowl) * 40 + grp * 8]);
                #pragma unroll
                for (int s = 0; s < 4; ++s)
                    acc[s][tt] = __builtin_amdgcn_mfma_f32_16x16x32_bf16(afrag[s], bfrag, acc[s][tt], 0, 0, 0);
            }
        }
        __syncthreads();   // everyone done reading Wlds
        if (kc + 1 < NC) {
            *reinterpret_cast<int4*>(&Wlds[wr0 * 40 + wq0 * 8]) = wreg0;
            if (u1 < TROWS4)
                *reinterpret_cast<int4*>(&Wlds[wr1 * 40 + wq1 * 8]) = wreg1;
        }
    }

    // ---- epilogue: bias + relu, store h (bf16), reduce over d -> out ----
    float bias_t[4];
    #pragma unroll
    for (int tt = 0; tt < 4; ++tt) {
        int oc = ncol0 + (tLo + tt) * 16 + rowl;
        bias_t[tt] = (tt < nTw && oc < 200) ? bias[oc] : 0.0f;
    }
    #pragma unroll
    for (int s = 0; s < 4; ++s) {
        int mrow0 = m0 + wM * 64 + s * 16;   // 16 rows = one batch index
        int bidx = mrow0 >> 4;
        #pragma unroll
        for (int tt = 0; tt < 4; ++tt) {
            if (tt < nTw) {
                int oc = ncol0 + (tLo + tt) * 16 + rowl;
                f32x4 v = acc[s][tt];
                float h0 = fmaxf(v[0] + bias_t[tt], 0.0f);
                float h1 = fmaxf(v[1] + bias_t[tt], 0.0f);
                float h2 = fmaxf(v[2] + bias_t[tt], 0.0f);
                float h3 = fmaxf(v[3] + bias_t[tt], 0.0f);
                if constexpr (LAYER < 2) {
                    size_t rb = (size_t)(mrow0 + grp * 4) * 208 + oc;
                    Hout[rb]             = f2bf_rne(h0);
                    Hout[rb + 208]       = f2bf_rne(h1);
                    Hout[rb + 2 * 208]   = f2bf_rne(h2);
                    Hout[rb + 3 * 208]   = f2bf_rne(h3);
                }
                float ssum = (h0 + h1) + (h2 + h3);   // 4 of the 16 d-rows
                ssum += __shfl_xor(ssum, 16);
                ssum += __shfl_xor(ssum, 32);
                if (grp == 0 && oc < 200)
                    out[(size_t)bidx * 600 + LAYER * 200 + oc] = ssum;
            }
        }
    }
}

// ---------------- launch ----------------
extern "C" void kernel_launch(void* const* d_in, const int* in_sizes, int n_in,
                              void* d_out, int out_size, void* d_ws, size_t ws_size,
                              hipStream_t stream) {
    const float* x  = (const float*)d_in[0];
    const float* W0 = (const float*)d_in[1];
    const float* b0 = (const float*)d_in[2];
    const float* W1 = (const float*)d_in[3];
    const float* b1 = (const float*)d_in[4];
    const float* W2 = (const float*)d_in[5];
    const float* b2 = (const float*)d_in[6];
    float* out = (float*)d_out;

    char* ws = (char*)d_ws;
    // workspace layout (all 16B aligned), total ~35.3 MB
    u16* xbd = (u16*)(ws);                                          // 32768*40*2   = 2,621,440
    u16* wp0 = (u16*)(ws + 2621440);                                // 208*1600*2   =   665,600
    u16* wp1 = (u16*)(ws + 2621440 + 665600);                       // 208*7808*2   = 3,248,128
    u16* wp2 = (u16*)(ws + 2621440 + 665600 + 3248128);             // 3,248,128
    u16* h1  = (u16*)(ws + 2621440 + 665600 + 2 * 3248128);         // 32768*208*2  = 13,631,488
    u16* h2  = (u16*)(ws + 2621440 + 665600 + 2 * 3248128 + 13631488);

    pack_x_kernel<<<5120, 256, 0, stream>>>(x, xbd);
    pack_w0_kernel<<<1300, 256, 0, stream>>>(W0, wp0);
    pack_w12_kernel<<<6344, 256, 0, stream>>>(W1, wp1);
    pack_w12_kernel<<<6344, 256, 0, stream>>>(W2, wp2);

    cin_gemm_kernel<0><<<512, 256, 0, stream>>>(xbd, (const u16*)nullptr, wp0, b0, h1, out);
    cin_gemm_kernel<1><<<512, 256, 0, stream>>>(xbd, h1, wp1, b1, h2, out);
    cin_gemm_kernel<2><<<512, 256, 0, stream>>>(xbd, h2, wp2, b2, (u16*)nullptr, out);
}

// Round 2
// 315.265 us; speedup vs baseline: 1.3548x; 1.3548x over previous
//
#include <hip/hip_runtime.h>
#include <hip/hip_bf16.h>
#include <stdint.h>

typedef __attribute__((ext_vector_type(8))) short bf16x8;
typedef __attribute__((ext_vector_type(4))) float f32x4;
typedef unsigned short u16;
typedef unsigned int u32;

__device__ __forceinline__ u16 f2bf_rne(float v) {
    u32 u = __float_as_uint(v);
    u32 r = (u + 0x7fffu + ((u >> 16) & 1u)) >> 16;
    return (u16)r;
}

// ---------------- pack kernels ----------------

// x (2048,39,16) f32  ->  xbd [32768][40] bf16, m = b*16+d, col 39 zero-pad
__global__ void pack_x_kernel(const float* __restrict__ x, u16* __restrict__ xbd) {
    int idx = blockIdx.x * 256 + threadIdx.x;
    if (idx >= 32768 * 40) return;
    int m = idx / 40, f = idx - m * 40;
    int b = m >> 4, d = m & 15;
    float v = (f < 39) ? x[(b * 39 + f) * 16 + d] : 0.0f;
    xbd[idx] = f2bf_rne(v);
}

// W0 (200,39,39) f32 -> Wp [224][1600] bf16, k = f*40+g, zero-padded
__global__ void pack_w0_kernel(const float* __restrict__ W, u16* __restrict__ Wp) {
    int idx = blockIdx.x * 256 + threadIdx.x;
    if (idx >= 224 * 1600) return;
    int o = idx / 1600, k = idx - o * 1600;
    int f = k / 40, g = k - f * 40;
    float v = (o < 200 && f < 39 && g < 39) ? W[(o * 39 + f) * 39 + g] : 0.0f;
    Wp[idx] = f2bf_rne(v);
}

// W1/W2 (200,39,200) f32 -> Wp [224][8128] bf16, k = f*208+g, zero-padded
__global__ void pack_w12_kernel(const float* __restrict__ W, u16* __restrict__ Wp) {
    int idx = blockIdx.x * 256 + threadIdx.x;
    if (idx >= 224 * 8128) return;
    int o = idx / 8128, k = idx - o * 8128;
    int f = k / 208, g = k - f * 208;
    float v = (o < 200 && f < 39 && g < 200) ? W[o * 7800 + f * 200 + g] : 0.0f;
    Wp[idx] = f2bf_rne(v);
}

// ---------------- main GEMM kernel ----------------
// C[m,o] = sum_k A[m,k]*Wp[o,k],  A[m, f*GS+g] = xbd[m,f]*h[m,g]
// grid 256 = 128 M-blocks x 2 N-halves. block: 512 thr = 8 waves = 4 mg x 2 kg.
// M=256 rows/block; wave: Mr=4 subtiles (64 rows) x NT(7|6) N-tiles; kg splits K32 chunks.
template <int LAYER>
__global__ __launch_bounds__(512, 2) void cin_gemm2(
    const u16* __restrict__ Xbd,    // [32768][40] bf16
    const u16* __restrict__ Hin,    // [32768][208] bf16 (LAYER>0)
    const u16* __restrict__ Wp,     // [224][KP] bf16
    const float* __restrict__ bias, // [200] f32
    u16* __restrict__ Hout,         // [32768][208] bf16 (LAYER<2)
    float* __restrict__ out)        // [2048][600] f32
{
    constexpr int KP    = (LAYER == 0) ? 1600 : 8128;
    constexpr int NPAIR = KP / 64;
    constexpr int HSTR  = (LAYER == 0) ? 40 : 216;
    constexpr u32 MAGIC = (LAYER == 0) ? 3277u : 10083u;
    constexpr int SHIFT = (LAYER == 0) ? 17 : 21;
    constexpr int GCL   = (LAYER == 0) ? 32 : 200;   // g0 clamp (8-aligned, in-bounds)
    constexpr int GS    = (LAYER == 0) ? 40 : 208;   // k = f*GS + g
    constexpr int XOFF  = (LAYER == 0) ? 0 : 110592; // H region size (256*216*2)
    constexpr int WOFF  = XOFF + 20480;              // X region size (256*40*2)
    constexpr int SMEM  = (LAYER == 0) ? 114688 : 148992;

    __shared__ __align__(16) char smem[SMEM];
    u16* Hl = (u16*)smem;
    u16* Xl = (u16*)(smem + XOFF);
    u16* Wl = (u16*)(smem + WOFF);   // 2 chunks x [112][40] u16 (4480 u16 each)

    const int bid  = blockIdx.x;
    const int mblk = bid >> 1, nblk = bid & 1;
    const int m0    = mblk * 256;
    const int ncol0 = nblk * 112;
    const int NT    = nblk ? 6 : 7;
    const int tid  = threadIdx.x;
    const int lane = tid & 63, wid = tid >> 6;
    const int mg = wid & 3, kg = wid >> 2;
    const int rowl = lane & 15, grp = lane >> 4;

    // ---- stage X (once) ----
    for (int u = tid; u < 256 * 5; u += 512) {
        int r = u / 5, q = u - r * 5;
        *(int4*)&Xl[r * 40 + q * 8] = *(const int4*)&Xbd[(size_t)(m0 + r) * 40 + q * 8];
    }
    // ---- stage H (once) ----
    if constexpr (LAYER > 0) {
        for (int u = tid; u < 256 * 26; u += 512) {
            int r = u / 26, q = u - r * 26;
            *(int4*)&Hl[r * HSTR + q * 8] = *(const int4*)&Hin[(size_t)(m0 + r) * 208 + q * 8];
        }
    }
    // ---- stage W pair 0 (both chunks): 2 x 112 rows x 4 b128 units ----
    for (int u = tid; u < 896; u += 512) {
        int c = (u >= 448) ? 1 : 0;
        int uu = u - c * 448;
        int r = uu >> 2, q = uu & 3;
        *(int4*)&Wl[c * 4480 + r * 40 + q * 8] =
            *(const int4*)&Wp[(size_t)(ncol0 + r) * KP + c * 32 + q * 8];
    }
    __syncthreads();

    int xro[4], hro[4];
    #pragma unroll
    for (int s = 0; s < 4; ++s) {
        int r = mg * 64 + s * 16 + rowl;
        xro[s] = r * 40;
        hro[s] = r * HSTR;
    }
    const u16* Hb = (LAYER == 0) ? Xl : Hl;

    f32x4 acc[4][7];
    #pragma unroll
    for (int s = 0; s < 4; ++s)
        #pragma unroll
        for (int t = 0; t < 7; ++t) {
            f32x4 z = {0.f, 0.f, 0.f, 0.f};
            acc[s][t] = z;
        }

    // prefetch unit decomposition
    const int pc0 = (tid >= 448) ? 1 : 0;
    const int pu0 = tid - pc0 * 448;
    const int pr0 = pu0 >> 2, pq0 = pu0 & 3;
    const int pr1 = (tid + 64) >> 2, pq1 = (tid + 64) & 3;   // unit tid+512 -> chunk 1, uu=tid+64 (valid tid<384)

    int4 pre0, pre1;
    for (int pr = 0; pr < NPAIR; ++pr) {
        const bool pf = (pr + 1 < NPAIR);
        if (pf) {
            int kb = (pr + 1) * 64;
            pre0 = *(const int4*)&Wp[(size_t)(ncol0 + pr0) * KP + kb + pc0 * 32 + pq0 * 8];
            if (tid < 384)
                pre1 = *(const int4*)&Wp[(size_t)(ncol0 + pr1) * KP + kb + 32 + pq1 * 8];
        }
        // ---- build A fragments for my chunk ----
        int k0 = pr * 64 + kg * 32 + grp * 8;
        u32 f = ((u32)k0 * MAGIC) >> SHIFT;
        f = (f > 38u) ? 38u : f;
        int g0 = k0 - (int)f * GS;
        g0 = (g0 > GCL) ? GCL : g0;
        bf16x8 afrag[4];
        #pragma unroll
        for (int s = 0; s < 4; ++s) {
            u16 xs = Xl[xro[s] + (int)f];
            bf16x8 hv = *(const bf16x8*)&Hb[hro[s] + g0];
            float xf = __uint_as_float(((u32)xs) << 16);
            union { bf16x8 v; u32 w[4]; } hu, au;
            hu.v = hv;
            #pragma unroll
            for (int j = 0; j < 4; ++j) {
                float lo = __uint_as_float(hu.w[j] << 16);
                float hi = __uint_as_float(hu.w[j] & 0xffff0000u);
                float pl = xf * lo;
                float ph = xf * hi;
                u32 pk;
                asm("v_cvt_pk_bf16_f32 %0, %1, %2" : "=v"(pk) : "v"(pl), "v"(ph));
                au.w[j] = pk;
            }
            afrag[s] = au.v;
        }
        // ---- B fragments + MFMA ----
        const u16* wb = &Wl[kg * 4480 + rowl * 40 + grp * 8];
        #pragma unroll
        for (int t = 0; t < 7; ++t) {
            if (t < NT) {
                bf16x8 bfrag = *(const bf16x8*)&wb[t * 640];
                #pragma unroll
                for (int s = 0; s < 4; ++s)
                    acc[s][t] = __builtin_amdgcn_mfma_f32_16x16x32_bf16(afrag[s], bfrag, acc[s][t], 0, 0, 0);
            }
        }
        __syncthreads();
        if (pf) {
            *(int4*)&Wl[pc0 * 4480 + pr0 * 40 + pq0 * 8] = pre0;
            if (tid < 384)
                *(int4*)&Wl[4480 + pr1 * 40 + pq1 * 8] = pre1;
        }
        __syncthreads();
    }

    // ---- merge kg pair partials via LDS ----
    __syncthreads();
    float* red = (float*)smem;
    const int rbase = mg * 7168 + lane * 4;
    if (kg == 1) {
        #pragma unroll
        for (int s = 0; s < 4; ++s)
            #pragma unroll
            for (int t = 0; t < 7; ++t)
                if (t < NT)
                    *(f32x4*)&red[rbase + (s * 7 + t) * 256] = acc[s][t];
    }
    __syncthreads();

    if (kg == 0) {
        float bias_t[7];
        #pragma unroll
        for (int t = 0; t < 7; ++t) {
            int oc = ncol0 + t * 16 + rowl;
            bias_t[t] = (t < NT && oc < 200) ? bias[oc] : 0.0f;
        }
        #pragma unroll
        for (int s = 0; s < 4; ++s) {
            int mrow0 = m0 + mg * 64 + s * 16;   // 16 rows = one batch index
            int bidx = mrow0 >> 4;
            #pragma unroll
            for (int t = 0; t < 7; ++t) {
                if (t < NT) {
                    int oc = ncol0 + t * 16 + rowl;
                    f32x4 o = *(const f32x4*)&red[rbase + (s * 7 + t) * 256];
                    f32x4 v = acc[s][t];
                    float h0 = fmaxf(v[0] + o[0] + bias_t[t], 0.0f);
                    float h1 = fmaxf(v[1] + o[1] + bias_t[t], 0.0f);
                    float h2 = fmaxf(v[2] + o[2] + bias_t[t], 0.0f);
                    float h3 = fmaxf(v[3] + o[3] + bias_t[t], 0.0f);
                    if constexpr (LAYER < 2) {
                        size_t rb = (size_t)(mrow0 + grp * 4) * 208 + oc;
                        Hout[rb]           = f2bf_rne(h0);
                        Hout[rb + 208]     = f2bf_rne(h1);
                        Hout[rb + 2*208]   = f2bf_rne(h2);
                        Hout[rb + 3*208]   = f2bf_rne(h3);
                    }
                    float ssum = (h0 + h1) + (h2 + h3);
                    ssum += __shfl_xor(ssum, 16);
                    ssum += __shfl_xor(ssum, 32);
                    if (grp == 0 && oc < 200)
                        out[(size_t)bidx * 600 + LAYER * 200 + oc] = ssum;
                }
            }
        }
    }
}

// ---------------- launch ----------------
extern "C" void kernel_launch(void* const* d_in, const int* in_sizes, int n_in,
                              void* d_out, int out_size, void* d_ws, size_t ws_size,
                              hipStream_t stream) {
    const float* x  = (const float*)d_in[0];
    const float* W0 = (const float*)d_in[1];
    const float* b0 = (const float*)d_in[2];
    const float* W1 = (const float*)d_in[3];
    const float* b1 = (const float*)d_in[4];
    const float* W2 = (const float*)d_in[5];
    const float* b2 = (const float*)d_in[6];
    float* out = (float*)d_out;

    char* ws = (char*)d_ws;
    // workspace layout (16B aligned), total ~37.9 MB
    u16* xbd = (u16*)(ws);                     // 32768*40*2  = 2,621,440
    u16* wp0 = (u16*)(ws + 2621440);           // 224*1600*2  =   716,800
    u16* wp1 = (u16*)(ws + 3338240);           // 224*8128*2  = 3,641,344
    u16* wp2 = (u16*)(ws + 6979584);           // 3,641,344
    u16* h1  = (u16*)(ws + 10620928);          // 32768*208*2 = 13,631,488
    u16* h2  = (u16*)(ws + 24252416);          // 13,631,488

    pack_x_kernel<<<5120, 256, 0, stream>>>(x, xbd);
    pack_w0_kernel<<<1400, 256, 0, stream>>>(W0, wp0);
    pack_w12_kernel<<<7112, 256, 0, stream>>>(W1, wp1);
    pack_w12_kernel<<<7112, 256, 0, stream>>>(W2, wp2);

    cin_gemm2<0><<<256, 512, 0, stream>>>(xbd, (const u16*)nullptr, wp0, b0, h1, out);
    cin_gemm2<1><<<256, 512, 0, stream>>>(xbd, h1, wp1, b1, h2, out);
    cin_gemm2<2><<<256, 512, 0, stream>>>(xbd, h2, wp2, b2, (u16*)nullptr, out);
}

// Round 3
// 292.362 us; speedup vs baseline: 1.4610x; 1.0783x over previous
//
#include <hip/hip_runtime.h>
#include <hip/hip_bf16.h>
#include <stdint.h>

typedef __attribute__((ext_vector_type(8))) short bf16x8;
typedef __attribute__((ext_vector_type(4))) float f32x4;
typedef unsigned short u16;
typedef unsigned int u32;

#define GLL(gp, lp) __builtin_amdgcn_global_load_lds( \
    (const __attribute__((address_space(1))) void*)(gp), \
    (__attribute__((address_space(3))) void*)(lp), 16, 0, 0)

__device__ __forceinline__ u16 f2bf_rne(float v) {
    u32 u = __float_as_uint(v);
    u32 r = (u + 0x7fffu + ((u >> 16) & 1u)) >> 16;
    return (u16)r;
}

// ---------------- pack kernels ----------------

// x (2048,39,16) f32  ->  xbd [32768][40] bf16, m = b*16+d, col 39 zero-pad
__global__ void pack_x_kernel(const float* __restrict__ x, u16* __restrict__ xbd) {
    int idx = blockIdx.x * 256 + threadIdx.x;
    if (idx >= 32768 * 40) return;
    int m = idx / 40, f = idx - m * 40;
    int b = m >> 4, d = m & 15;
    float v = (f < 39) ? x[(b * 39 + f) * 16 + d] : 0.0f;
    xbd[idx] = f2bf_rne(v);
}

// W0 (200,39,39) f32 -> Wp [224][1600] bf16, k = f*40+g, zero-padded
__global__ void pack_w0_kernel(const float* __restrict__ W, u16* __restrict__ Wp) {
    int idx = blockIdx.x * 256 + threadIdx.x;
    if (idx >= 224 * 1600) return;
    int o = idx / 1600, k = idx - o * 1600;
    int f = k / 40, g = k - f * 40;
    float v = (o < 200 && f < 39 && g < 39) ? W[(o * 39 + f) * 39 + g] : 0.0f;
    Wp[idx] = f2bf_rne(v);
}

// W1/W2 (200,39,200) f32 -> Wp [224][8128] bf16, k = f*208+g, zero-padded
__global__ void pack_w12_kernel(const float* __restrict__ W, u16* __restrict__ Wp) {
    int idx = blockIdx.x * 256 + threadIdx.x;
    if (idx >= 224 * 8128) return;
    int o = idx / 8128, k = idx - o * 8128;
    int f = k / 208, g = k - f * 208;
    float v = (o < 200 && f < 39 && g < 200) ? W[o * 7800 + f * 200 + g] : 0.0f;
    Wp[idx] = f2bf_rne(v);
}

// ---------------- main GEMM kernel ----------------
// C[m,o] = sum_k A[m,k]*Wp[o,k],  A[m, f*GS+g] = xbd[m,f]*h[m,g]
// grid 256 = 128 M-blocks x 2 N-halves. block: 512 thr = 8 waves = 4 mg x 2 kg.
// W streamed via global_load_lds into double-buffered LDS; ONE barrier per 64-K pair.
template <int LAYER>
__global__ __launch_bounds__(512, 2) void cin_gemm3(
    const u16* __restrict__ Xbd,    // [32768][40] bf16
    const u16* __restrict__ Hin,    // [32768][208] bf16 (LAYER>0)
    const u16* __restrict__ Wp,     // [224][KP] bf16
    const float* __restrict__ bias, // [200] f32
    u16* __restrict__ Hout,         // [32768][208] bf16 (LAYER<2)
    float* __restrict__ out)        // [2048][600] f32
{
    constexpr int KP    = (LAYER == 0) ? 1600 : 8128;
    constexpr int NPAIR = KP / 64;
    constexpr u32 MAGIC = (LAYER == 0) ? 3277u : 10083u;
    constexpr int SHIFT = (LAYER == 0) ? 17 : 21;
    constexpr int GS    = (LAYER == 0) ? 40 : 208;     // k = f*GS + g
    constexpr int HROW  = (LAYER == 0) ? 40 : 208;     // LDS row stride (elements)
    constexpr int HSZ   = (LAYER == 0) ? 0 : 106496;   // 256*208*2
    constexpr int WOFF  = 20480 + HSZ;                 // X region = 256*40*2
    constexpr int SMEMA = WOFF + 28672;                // + W dbuf 2*14336
    constexpr int SMEM  = (SMEMA > 117760) ? SMEMA : 117760;  // epilogue red[] needs 117760

    __shared__ __align__(16) char smem[SMEM];
    u16* Xl = (u16*)smem;
    u16* Hl = (u16*)(smem + 20480);

    const int bid  = blockIdx.x;
    const int mblk = bid >> 1, nblk = bid & 1;
    const int m0    = mblk * 256;
    const int ncol0 = nblk * 112;
    const int NT    = nblk ? 6 : 7;
    const int tid  = threadIdx.x;
    const int lane = tid & 63, wid = tid >> 6;
    const int mg = wid & 3, kg = wid >> 2;
    const int rowl = lane & 15, grp = lane >> 4;

    // ---- per-thread W staging global offsets (loop-invariant) ----
    int goff0, goff1;
    {
        int u = wid * 64 + lane;
        int c = (u >= 448) ? 1 : 0;
        int uu = u - c * 448;
        goff0 = (ncol0 + (uu >> 2)) * KP + c * 32 + (uu & 3) * 8;
        int u1 = (wid + 8) * 64 + lane;     // valid when wid < 6
        int uu1 = u1 - 448;
        goff1 = (ncol0 + (uu1 >> 2)) * KP + 32 + (uu1 & 3) * 8;
    }

    // ---- stage X (once) ----
    {
        const char* xsrc = (const char*)(Xbd + (size_t)m0 * 40);
        for (int i = wid; i < 20; i += 8)
            GLL(xsrc + i * 1024 + lane * 16, smem + i * 1024);
    }
    // ---- stage H (once) ----
    if constexpr (LAYER > 0) {
        const char* hsrc = (const char*)(Hin + (size_t)m0 * 208);
        for (int i = wid; i < 104; i += 8)
            GLL(hsrc + i * 1024 + lane * 16, smem + 20480 + i * 1024);
    }
    // ---- stage W pair 0 ----
    {
        const u16* gsrc = Wp;
        char* wb = smem + WOFF;
        GLL((const char*)(gsrc + goff0), wb + wid * 1024);
        if (wid < 6) GLL((const char*)(gsrc + goff1), wb + wid * 1024 + 8192);
    }

    int xro[4], hro[4];
    #pragma unroll
    for (int s = 0; s < 4; ++s) {
        int r = mg * 64 + s * 16 + rowl;
        xro[s] = r * 40;
        hro[s] = r * HROW;
    }
    const u16* Hb = (LAYER == 0) ? Xl : Hl;

    f32x4 acc[4][7];
    #pragma unroll
    for (int s = 0; s < 4; ++s)
        #pragma unroll
        for (int t = 0; t < 7; ++t) {
            f32x4 z = {0.f, 0.f, 0.f, 0.f};
            acc[s][t] = z;
        }

    for (int pr = 0; pr < NPAIR; ++pr) {
        __syncthreads();   // drains this wave's W loads (vmcnt 0) + syncs buffers
        // issue W loads for pair pr+1 into the other buffer (land by next barrier)
        if (pr + 1 < NPAIR) {
            const u16* gsrc = Wp + (size_t)(pr + 1) * 64;
            char* wb = smem + WOFF + ((pr + 1) & 1) * 14336;
            GLL((const char*)(gsrc + goff0), wb + wid * 1024);
            if (wid < 6) GLL((const char*)(gsrc + goff1), wb + wid * 1024 + 8192);
        }
        // ---- build A fragments for my chunk ----
        int k0 = pr * 64 + kg * 32 + grp * 8;
        u32 f = ((u32)k0 * MAGIC) >> SHIFT;
        int g0 = k0 - (int)f * GS;
        bf16x8 afrag[4];
        #pragma unroll
        for (int s = 0; s < 4; ++s) {
            u16 xs = Xl[xro[s] + (int)f];
            bf16x8 hv = *(const bf16x8*)&Hb[hro[s] + g0];
            float xf = __uint_as_float(((u32)xs) << 16);
            union { bf16x8 v; u32 w[4]; } hu, au;
            hu.v = hv;
            #pragma unroll
            for (int j = 0; j < 4; ++j) {
                float lo = __uint_as_float(hu.w[j] << 16);
                float hi = __uint_as_float(hu.w[j] & 0xffff0000u);
                float pl = xf * lo;
                float ph = xf * hi;
                u32 pk;
                asm("v_cvt_pk_bf16_f32 %0, %1, %2" : "=v"(pk) : "v"(pl), "v"(ph));
                au.w[j] = pk;
            }
            afrag[s] = au.v;
        }
        // ---- B fragments + MFMA ----
        const u16* wbR = (const u16*)(smem + WOFF + (pr & 1) * 14336) + kg * 3584 + rowl * 32 + grp * 8;
        #pragma unroll
        for (int t = 0; t < 7; ++t) {
            if (t < NT) {
                bf16x8 bfrag = *(const bf16x8*)&wbR[t * 512];
                #pragma unroll
                for (int s = 0; s < 4; ++s)
                    acc[s][t] = __builtin_amdgcn_mfma_f32_16x16x32_bf16(afrag[s], bfrag, acc[s][t], 0, 0, 0);
            }
        }
    }

    // ---- merge kg pair partials via LDS (reuses smem; X/H/W dead) ----
    __syncthreads();
    float* red = (float*)smem;
    const int rbase = mg * 7168 + lane * 4;
    if (kg == 1) {
        #pragma unroll
        for (int s = 0; s < 4; ++s)
            #pragma unroll
            for (int t = 0; t < 7; ++t)
                if (t < NT)
                    *(f32x4*)&red[rbase + (s * 7 + t) * 256] = acc[s][t];
    }
    __syncthreads();

    if (kg == 0) {
        float bias_t[7];
        #pragma unroll
        for (int t = 0; t < 7; ++t) {
            int oc = ncol0 + t * 16 + rowl;
            bias_t[t] = (t < NT && oc < 200) ? bias[oc] : 0.0f;
        }
        #pragma unroll
        for (int s = 0; s < 4; ++s) {
            int mrow0 = m0 + mg * 64 + s * 16;   // 16 rows = one batch index
            int bidx = mrow0 >> 4;
            #pragma unroll
            for (int t = 0; t < 7; ++t) {
                if (t < NT) {
                    int oc = ncol0 + t * 16 + rowl;
                    f32x4 o = *(const f32x4*)&red[rbase + (s * 7 + t) * 256];
                    f32x4 v = acc[s][t];
                    float h0 = fmaxf(v[0] + o[0] + bias_t[t], 0.0f);
                    float h1 = fmaxf(v[1] + o[1] + bias_t[t], 0.0f);
                    float h2 = fmaxf(v[2] + o[2] + bias_t[t], 0.0f);
                    float h3 = fmaxf(v[3] + o[3] + bias_t[t], 0.0f);
                    if constexpr (LAYER < 2) {
                        size_t rb = (size_t)(mrow0 + grp * 4) * 208 + oc;
                        Hout[rb]           = f2bf_rne(h0);
                        Hout[rb + 208]     = f2bf_rne(h1);
                        Hout[rb + 2*208]   = f2bf_rne(h2);
                        Hout[rb + 3*208]   = f2bf_rne(h3);
                    }
                    float ssum = (h0 + h1) + (h2 + h3);
                    ssum += __shfl_xor(ssum, 16);
                    ssum += __shfl_xor(ssum, 32);
                    if (grp == 0 && oc < 200)
                        out[(size_t)bidx * 600 + LAYER * 200 + oc] = ssum;
                }
            }
        }
    }
}

// ---------------- launch ----------------
extern "C" void kernel_launch(void* const* d_in, const int* in_sizes, int n_in,
                              void* d_out, int out_size, void* d_ws, size_t ws_size,
                              hipStream_t stream) {
    const float* x  = (const float*)d_in[0];
    const float* W0 = (const float*)d_in[1];
    const float* b0 = (const float*)d_in[2];
    const float* W1 = (const float*)d_in[3];
    const float* b1 = (const float*)d_in[4];
    const float* W2 = (const float*)d_in[5];
    const float* b2 = (const float*)d_in[6];
    float* out = (float*)d_out;

    char* ws = (char*)d_ws;
    // workspace layout (16B aligned), total ~37.9 MB
    u16* xbd = (u16*)(ws);                     // 32768*40*2  = 2,621,440
    u16* wp0 = (u16*)(ws + 2621440);           // 224*1600*2  =   716,800
    u16* wp1 = (u16*)(ws + 3338240);           // 224*8128*2  = 3,641,344
    u16* wp2 = (u16*)(ws + 6979584);           // 3,641,344
    u16* h1  = (u16*)(ws + 10620928);          // 32768*208*2 = 13,631,488
    u16* h2  = (u16*)(ws + 24252416);          // 13,631,488

    pack_x_kernel<<<5120, 256, 0, stream>>>(x, xbd);
    pack_w0_kernel<<<1400, 256, 0, stream>>>(W0, wp0);
    pack_w12_kernel<<<7112, 256, 0, stream>>>(W1, wp1);
    pack_w12_kernel<<<7112, 256, 0, stream>>>(W2, wp2);

    cin_gemm3<0><<<256, 512, 0, stream>>>(xbd, (const u16*)nullptr, wp0, b0, h1, out);
    cin_gemm3<1><<<256, 512, 0, stream>>>(xbd, h1, wp1, b1, h2, out);
    cin_gemm3<2><<<256, 512, 0, stream>>>(xbd, h2, wp2, b2, (u16*)nullptr, out);
}